// Round 6
// baseline (4621.840 us; speedup 1.0000x reference)
//
#include <hip/hip_runtime.h>
#include <math.h>

#define Bsz 1024
#define Lsz 50
#define Esz 256
#define Hsz 256
#define NEGV (-1e9f)

// async global->LDS 16B copy: per-lane global addr, wave-uniform LDS base
// (HW writes base + lane*16).  Falls back to reg staging if unavailable.
__device__ __forceinline__ void gl_lds16(const float* g, float* l) {
#if __has_builtin(__builtin_amdgcn_global_load_lds)
    __builtin_amdgcn_global_load_lds(
        (const __attribute__((address_space(1))) unsigned int*)g,
        (__attribute__((address_space(3))) unsigned int*)l, 16, 0, 0);
#else
    *(float4*)l = *(const float4*)g;
#endif
}

// ============================================================
// e-projection GEMM (one-time) + Wq k-major pack fused into one
// dispatch.  Blocks [0,6400): eproj exactly as the verified kernel
// (XCD-partitioned m-tiles, reg prefetch, LDS stride 68).
// Blocks [6400,6912): pack_wq (trivial, runs in eproj's shadow).
// ============================================================
__global__ __launch_bounds__(256) void eproj_pack(
    const float* __restrict__ A,
    const float* __restrict__ Wgl, const float* __restrict__ bgl, float* __restrict__ Egl,
    const float* __restrict__ Wpt, const float* __restrict__ bpt, float* __restrict__ Ept,
    const float* __restrict__ WqGl, const float* __restrict__ WqPt,
    float* __restrict__ WqGlP, float* __restrict__ WqPtP)
{
    __shared__ __align__(16) float As[16][68];
    __shared__ __align__(16) float Bs[16][68];
    const int tid = threadIdx.x;

    if (blockIdx.x >= 6400) {
        // ---- pack branch: Wpk[((k>>2)*256 + n)*4 + (k&3)] = Wq[n][k] ----
        const int p = blockIdx.x - 6400;       // [0,512)
        const int sel = p >> 8;
        const int k = p & 255;
        const float* src = sel ? WqPt : WqGl;
        float*       dst = sel ? WqPtP : WqGlP;
        dst[((size_t)(k >> 2) * 256 + tid) * 4 + (k & 3)] = src[(size_t)tid * 256 + k];
        return;
    }

    const int tx = tid & 15, ty = tid >> 4;
    const int ml = tid >> 2;
    const int kb = (tid & 3) << 2;

    const int x = blockIdx.x;
    const int xcd = x & 7;
    const int j = x >> 3;
    const int mt = xcd * 100 + (j >> 3);
    const int sel = (j >> 2) & 1;
    const int nt = j & 3;
    const float* W    = sel ? Wpt : Wgl;
    const float* bias = sel ? bpt : bgl;
    float*       Eo   = sel ? Ept : Egl;
    const int m0 = mt * 64, n0 = nt * 64;

    float4 a4 = *(const float4*)(A + (size_t)(m0 + ml) * 256 + kb);
    float4 b4 = *(const float4*)(W + (size_t)(n0 + ml) * 256 + kb);

    float acc[4][4] = {};
    for (int k0 = 0; k0 < 256; k0 += 16) {
        As[kb+0][ml] = a4.x; As[kb+1][ml] = a4.y; As[kb+2][ml] = a4.z; As[kb+3][ml] = a4.w;
        Bs[kb+0][ml] = b4.x; Bs[kb+1][ml] = b4.y; Bs[kb+2][ml] = b4.z; Bs[kb+3][ml] = b4.w;
        __syncthreads();
        int k1 = k0 + 16;
        if (k1 < 256) {
            a4 = *(const float4*)(A + (size_t)(m0 + ml) * 256 + k1 + kb);
            b4 = *(const float4*)(W + (size_t)(n0 + ml) * 256 + k1 + kb);
        }
#pragma unroll
        for (int kk = 0; kk < 16; kk++) {
            float4 av = *(const float4*)(&As[kk][ty << 2]);
            float4 bv = *(const float4*)(&Bs[kk][tx << 2]);
            float a_[4] = {av.x, av.y, av.z, av.w};
            float b_[4] = {bv.x, bv.y, bv.z, bv.w};
#pragma unroll
            for (int i = 0; i < 4; i++)
#pragma unroll
                for (int j2 = 0; j2 < 4; j2++) acc[i][j2] = fmaf(a_[i], b_[j2], acc[i][j2]);
        }
        __syncthreads();
    }
#pragma unroll
    for (int i = 0; i < 4; i++) {
        int m = m0 + (ty << 2) + i;
        int bb = m & (Bsz - 1);
        int ll = m >> 10;
#pragma unroll
        for (int j2 = 0; j2 < 4; j2++) {
            int n = n0 + (tx << 2) + j2;
            Eo[(size_t)bb * Lsz * Hsz + (size_t)ll * Hsz + n] = acc[i][j2] + bias[n];
        }
    }
}

// ============================================================
// K1: fused LSTM, 32 rows x 64 gate-cols per block -> 512 blocks.
// Verbatim round-0 kernel (best-measured LSTM shape).
// ============================================================
__global__ __launch_bounds__(256) void lstm_fused(
    const float* __restrict__ dec, const float* __restrict__ hprev,
    const float* __restrict__ cin,
    const float* __restrict__ Wih, const float* __restrict__ Whh,
    const float* __restrict__ bih, const float* __restrict__ bhh,
    float* __restrict__ hout, float* __restrict__ cout)
{
    __shared__ __align__(16) float As[16][36];
    __shared__ __align__(16) float Bs[16][68];
    const int tid = threadIdx.x;
    const int tx = tid & 15, ty = tid >> 4;
    const int mlA = tid >> 3;
    const int kbA = (tid & 7) << 1;
    const int mlB = tid >> 2;
    const int kbB = (tid & 3) << 2;
    const int m0 = blockIdx.x * 32;
    const int hh0 = blockIdx.y * 16;
    const int wrow = ((mlB >> 4) << 8) + hh0 + (mlB & 15);
    const int pcol = ((mlB & 15) << 2) + (mlB >> 4);

    float2 a2 = *(const float2*)(dec + (size_t)(m0 + mlA) * 256 + kbA);
    float4 b4 = *(const float4*)(Wih + (size_t)wrow * 256 + kbB);

    float acc[2][4] = {};
    for (int k0 = 0; k0 < 512; k0 += 16) {
        As[kbA+0][mlA] = a2.x; As[kbA+1][mlA] = a2.y;
        Bs[kbB+0][pcol] = b4.x; Bs[kbB+1][pcol] = b4.y;
        Bs[kbB+2][pcol] = b4.z; Bs[kbB+3][pcol] = b4.w;
        __syncthreads();
        int k1 = k0 + 16;
        if (k1 < 512) {
            const float* Ap = (k1 < 256) ? dec : hprev;
            const float* Wp = (k1 < 256) ? Wih : Whh;
            int kk0 = k1 & 255;
            a2 = *(const float2*)(Ap + (size_t)(m0 + mlA) * 256 + kk0 + kbA);
            b4 = *(const float4*)(Wp + (size_t)wrow * 256 + kk0 + kbB);
        }
#pragma unroll
        for (int kk = 0; kk < 16; kk++) {
            float2 av = *(const float2*)(&As[kk][ty << 1]);
            float4 bv = *(const float4*)(&Bs[kk][tx << 2]);
            acc[0][0] = fmaf(av.x, bv.x, acc[0][0]);
            acc[0][1] = fmaf(av.x, bv.y, acc[0][1]);
            acc[0][2] = fmaf(av.x, bv.z, acc[0][2]);
            acc[0][3] = fmaf(av.x, bv.w, acc[0][3]);
            acc[1][0] = fmaf(av.y, bv.x, acc[1][0]);
            acc[1][1] = fmaf(av.y, bv.y, acc[1][1]);
            acc[1][2] = fmaf(av.y, bv.z, acc[1][2]);
            acc[1][3] = fmaf(av.y, bv.w, acc[1][3]);
        }
        __syncthreads();
    }

    const int hh = hh0 + tx;
    const float bi0 = bih[hh]       + bhh[hh];
    const float bf  = bih[256 + hh] + bhh[256 + hh];
    const float bg  = bih[512 + hh] + bhh[512 + hh];
    const float bo  = bih[768 + hh] + bhh[768 + hh];
#pragma unroll
    for (int i = 0; i < 2; i++) {
        int m = m0 + (ty << 1) + i;
        float gi = acc[i][0] + bi0;
        float gf = acc[i][1] + bf;
        float gc = acc[i][2] + bg;
        float go = acc[i][3] + bo;
        float ii = 1.0f / (1.0f + expf(-gi));
        float ff = 1.0f / (1.0f + expf(-gf));
        float oo = 1.0f / (1.0f + expf(-go));
        float c2 = ff * cin[(size_t)m * 256 + hh] + ii * tanhf(gc);
        hout[(size_t)m * 256 + hh] = oo * tanhf(c2);
        cout[(size_t)m * 256 + hh] = c2;
    }
}

// ============================================================
// K2: fused glimpse + pointer attention, ONE row per block,
// 512 threads (8 waves), 1024 blocks, __launch_bounds__(512,8)
// -> 4 blocks/CU (32 waves/CU), LDS 35.6KB <= 40KB (all resident).
//  * u-phases: l = lp*8 + wave -> 7 serial iters (was 13); per-l
//    chain (lane map, tanh order, shfl order) unchanged -> bit-exact.
//  * gl-matvec runs on waves 0-3 (same 16 active waves/CU as
//    before); waves 4-7 async-prefetch e_gl rows 0-31 into e_ls.
//  * glimpse-u + mix read e_gl rows <32 from LDS (same bytes).
//  * during pt-matvec, waves 4-7 refill e_ls with e_pt rows 0-31
//    (issued after all e_gl readers' barrier; visible via the
//    issuing wave's vmcnt drain at its barrier).
//  * pointer-u reads rows <32 from LDS as in round 5.
// ============================================================
__global__ __launch_bounds__(512, 8) void attn_row(
    const float* __restrict__ h,
    const float* __restrict__ WqGlP, const float* __restrict__ glbq,
    const float* __restrict__ e_gl, const float* __restrict__ glv,
    const float* __restrict__ WqPtP, const float* __restrict__ ptbq,
    const float* __restrict__ e_pt, const float* __restrict__ ptv,
    int* __restrict__ mask, float* __restrict__ out, int t,
    float* __restrict__ dec, const float* __restrict__ emb)
{
    __shared__ __align__(16) float e_ls[32][256];   // e prefetch (32KB)
    __shared__ __align__(16) float h_s[256];
    __shared__ __align__(16) float q_s[256];
    __shared__ __align__(16) float g_s[256];
    __shared__ float u_s[64];
    __shared__ float p_s[64];
    __shared__ int sel_s;

    const int tid = threadIdx.x;
    const int lane = tid & 63, wave = tid >> 6;     // 8 waves
    const int b = blockIdx.x;

    const float* ebg = e_gl + (size_t)b * Lsz * 256;
    const float* ebp = e_pt + (size_t)b * Lsz * 256;

    if (tid < 256) h_s[tid] = h[(size_t)b * 256 + tid];
    __syncthreads();

    // ---- glimpse query matvec (waves 0-3) ∥ e_gl prefetch (waves 4-7) ----
    if (tid < 256) {
        float q = glbq[tid];
        const float4* Wp = (const float4*)WqGlP;
#pragma unroll 8
        for (int k4 = 0; k4 < 64; k4++) {
            float4 w  = Wp[(size_t)k4 * 256 + tid];
            float4 hv = ((const float4*)h_s)[k4];
            q = fmaf(hv.x, w.x, q);
            q = fmaf(hv.y, w.y, q);
            q = fmaf(hv.z, w.z, q);
            q = fmaf(hv.w, w.w, q);
        }
        q_s[tid] = q;
    } else {
        const int r0 = (wave - 4) * 8;
#pragma unroll
        for (int j = 0; j < 8; j++)
            gl_lds16(ebg + (size_t)(r0 + j) * 256 + (lane << 2), &e_ls[r0 + j][0]);
    }
    __syncthreads();

    // ---- glimpse u: 8 waves, 7 serial iters ----
    {
        const float4 q4 = ((const float4*)q_s)[lane];
        const float4 v4 = ((const float4*)glv)[lane];
#pragma unroll
        for (int lp = 0; lp < 7; lp++) {
            const int l = lp * 8 + wave;
            float x = 0.0f;
            if (l < Lsz) {
                float4 e4;
                if (lp < 4) e4 = *(const float4*)(&e_ls[l][lane << 2]);
                else        e4 = *(const float4*)(ebg + (size_t)l * 256 + (lane << 2));
                x  = v4.x * tanhf(q4.x + e4.x);
                x += v4.y * tanhf(q4.y + e4.y);
                x += v4.z * tanhf(q4.z + e4.z);
                x += v4.w * tanhf(q4.w + e4.w);
            }
#pragma unroll
            for (int o = 32; o > 0; o >>= 1) x += __shfl_xor(x, o, 64);
            if (lane == 0 && l < Lsz) u_s[l] = x;
        }
    }
    __syncthreads();

    // ---- glimpse softmax (wave 0, lane-parallel) ----
    if (wave == 0) {
        const int l = lane;
        const int ml = (l < Lsz && t > 0) ? mask[b * Lsz + l] : 0;
        float logit = (l < Lsz) ? (ml ? NEGV : u_s[l]) : -1e30f;
        float m = logit;
#pragma unroll
        for (int o = 32; o > 0; o >>= 1) m = fmaxf(m, __shfl_xor(m, o, 64));
        float ex = (l < Lsz) ? expf(logit - m) : 0.0f;
        float den = ex;
#pragma unroll
        for (int o = 32; o > 0; o >>= 1) den += __shfl_xor(den, o, 64);
        if (l < Lsz) p_s[l] = ex / den;
    }
    __syncthreads();

    // ---- glimpse mix (rows <32 from LDS, rest L2-hot; exact l order) ----
    if (tid < 256) {
        float acc = 0.0f;
        const float* ebh = ebg + tid;
#pragma unroll
        for (int l = 0; l < Lsz; l++) {
            float ev = (l < 32) ? e_ls[l][tid] : ebh[(size_t)l * 256];
            acc = fmaf(p_s[l], ev, acc);
        }
        g_s[tid] = acc;
    }
    __syncthreads();

    // ---- pointer query matvec (waves 0-3) ∥ e_pt prefetch (waves 4-7) ----
    if (tid < 256) {
        float p = ptbq[tid];
        const float4* Wp = (const float4*)WqPtP;
#pragma unroll 8
        for (int k4 = 0; k4 < 64; k4++) {
            float4 w  = Wp[(size_t)k4 * 256 + tid];
            float4 gv = ((const float4*)g_s)[k4];
            p = fmaf(gv.x, w.x, p);
            p = fmaf(gv.y, w.y, p);
            p = fmaf(gv.z, w.z, p);
            p = fmaf(gv.w, w.w, p);
        }
        q_s[tid] = p;
    } else {
        const int r0 = (wave - 4) * 8;
#pragma unroll
        for (int j = 0; j < 8; j++)
            gl_lds16(ebp + (size_t)(r0 + j) * 256 + (lane << 2), &e_ls[r0 + j][0]);
    }
    __syncthreads();

    // ---- pointer u: 8 waves, 7 serial iters ----
    {
        const float4 q4 = ((const float4*)q_s)[lane];
        const float4 v4 = ((const float4*)ptv)[lane];
#pragma unroll
        for (int lp = 0; lp < 7; lp++) {
            const int l = lp * 8 + wave;
            float x = 0.0f;
            if (l < Lsz) {
                float4 e4;
                if (lp < 4) e4 = *(const float4*)(&e_ls[l][lane << 2]);
                else        e4 = *(const float4*)(ebp + (size_t)l * 256 + (lane << 2));
                x  = v4.x * tanhf(q4.x + e4.x);
                x += v4.y * tanhf(q4.y + e4.y);
                x += v4.z * tanhf(q4.z + e4.z);
                x += v4.w * tanhf(q4.w + e4.w);
            }
#pragma unroll
            for (int o = 32; o > 0; o >>= 1) x += __shfl_xor(x, o, 64);
            if (lane == 0 && l < Lsz) u_s[l] = x;
        }
    }
    __syncthreads();

    // ---- pointer softmax + argmax + log_p + mask update (wave 0) ----
    if (wave == 0) {
        const int l = lane;
        const int ml = (l < Lsz && t > 0) ? mask[b * Lsz + l] : 0;
        float logit;
        if (l < Lsz) {
            float u = u_s[l];
            logit = 10.0f * tanhf(u);
            if (ml) logit = NEGV;
        } else logit = -1e30f;

        float m = logit;
#pragma unroll
        for (int o = 32; o > 0; o >>= 1) m = fmaxf(m, __shfl_xor(m, o, 64));
        float ex = (l < Lsz) ? expf(logit - m) : 0.0f;
        float den = ex;
#pragma unroll
        for (int o = 32; o > 0; o >>= 1) den += __shfl_xor(den, o, 64);

        // argmax with first-index tie-break
        float av = logit; int ai = (l < Lsz) ? l : 63;
#pragma unroll
        for (int o = 32; o > 0; o >>= 1) {
            float ov = __shfl_xor(av, o, 64);
            int   oi = __shfl_xor(ai, o, 64);
            if (ov > av || (ov == av && oi < ai)) { av = ov; ai = oi; }
        }
        const float lse = m + logf(den);
        if (l < Lsz)
            out[(size_t)b * Lsz * Lsz + (size_t)t * Lsz + l] = logit - lse;
        if (l == 0) {
            out[(size_t)Bsz * Lsz * Lsz + (size_t)b * Lsz + t] = (float)ai;
            sel_s = ai;
        }
        int newm = ml | (l == ai);
        unsigned long long bal = __ballot(l >= Lsz ? 1 : newm);
        int all = (bal == 0xFFFFFFFFFFFFFFFFull);
        if (l < Lsz) mask[b * Lsz + l] = (all && l == Lsz - 1) ? 0 : newm;
    }
    __syncthreads();

    // ---- gather next decoder input ----
    if (tid < 256) {
        const int s = sel_s;
        dec[(size_t)b * 256 + tid] = emb[(size_t)s * Bsz * 256 + (size_t)b * 256 + tid];
    }
}

// ============================================================
extern "C" void kernel_launch(void* const* d_in, const int* in_sizes, int n_in,
                              void* d_out, int out_size, void* d_ws, size_t ws_size,
                              hipStream_t stream) {
    const float* decoder_input = (const float*)d_in[0];
    const float* emb           = (const float*)d_in[1];   // [L,B,E]
    const float* h0            = (const float*)d_in[2];
    const float* c0            = (const float*)d_in[3];
    const float* context       = (const float*)d_in[4];   // [L,B,H]
    const float* Wih    = (const float*)d_in[6];
    const float* Whh    = (const float*)d_in[7];
    const float* bih    = (const float*)d_in[8];
    const float* bhh    = (const float*)d_in[9];
    const float* glWq   = (const float*)d_in[10];
    const float* glbq   = (const float*)d_in[11];
    const float* glWref = (const float*)d_in[12];
    const float* glbref = (const float*)d_in[13];
    const float* glv    = (const float*)d_in[14];
    const float* ptWq   = (const float*)d_in[15];
    const float* ptbq   = (const float*)d_in[16];
    const float* ptWref = (const float*)d_in[17];
    const float* ptbref = (const float*)d_in[18];
    const float* ptv    = (const float*)d_in[19];

    float* out = (float*)d_out;

    // workspace layout (floats)
    float* ws    = (float*)d_ws;
    float* e_gl  = ws;                                    // [B,L,H]
    float* e_pt  = e_gl + (size_t)Bsz * Lsz * Hsz;        // [B,L,H]
    float* WqGlP = e_pt + (size_t)Bsz * Lsz * Hsz;        // [H,H] packed
    float* WqPtP = WqGlP + (size_t)Hsz * Hsz;
    float* hb0   = WqPtP + (size_t)Hsz * Hsz;
    float* hb1   = hb0 + (size_t)Bsz * Hsz;
    float* cb0   = hb1 + (size_t)Bsz * Hsz;
    float* cb1   = cb0 + (size_t)Bsz * Hsz;
    float* dec   = cb1 + (size_t)Bsz * Hsz;
    int*   mask  = (int*)(dec + (size_t)Bsz * Esz);       // [B,L]

    float* hbuf[2] = {hb0, hb1};
    float* cbuf[2] = {cb0, cb1};

    // one-time: e-projection GEMMs + Wq pack, single dispatch
    eproj_pack<<<dim3(6912), dim3(256), 0, stream>>>(
        context, glWref, glbref, e_gl, ptWref, ptbref, e_pt,
        glWq, ptWq, WqGlP, WqPtP);

    for (int t = 0; t < Lsz; t++) {
        const float* Ain = (t == 0) ? decoder_input : dec;
        const float* hin = (t == 0) ? h0 : hbuf[(t + 1) & 1];
        const float* cin = (t == 0) ? c0 : cbuf[(t + 1) & 1];
        float* hout = hbuf[t & 1];
        float* cout = cbuf[t & 1];

        lstm_fused<<<dim3(32, 16), dim3(256), 0, stream>>>(
            Ain, hin, cin, Wih, Whh, bih, bhh, hout, cout);

        attn_row<<<dim3(1024), dim3(512), 0, stream>>>(
            hout, WqGlP, glbq, e_gl, glv, WqPtP, ptbq, e_pt, ptv,
            mask, out, t, dec, emb);
    }
}

// Round 7
// 4085.939 us; speedup vs baseline: 1.1312x; 1.1312x over previous
//
#include <hip/hip_runtime.h>
#include <math.h>

#define Bsz 1024
#define Lsz 50
#define Esz 256
#define Hsz 256
#define NEGV (-1e9f)

// async global->LDS 16B copy: per-lane global addr, wave-uniform LDS base
// (HW writes base + lane*16).  Falls back to reg staging if unavailable.
__device__ __forceinline__ void gl_lds16(const float* g, float* l) {
#if __has_builtin(__builtin_amdgcn_global_load_lds)
    __builtin_amdgcn_global_load_lds(
        (const __attribute__((address_space(1))) unsigned int*)g,
        (__attribute__((address_space(3))) unsigned int*)l, 16, 0, 0);
#else
    *(float4*)l = *(const float4*)g;
#endif
}

// ============================================================
// e-projection GEMM (one-time) + Wq k-major pack fused into one
// dispatch.  Blocks [0,6400): eproj exactly as the verified kernel.
// Blocks [6400,6912): pack_wq (runs in eproj's shadow).
// ============================================================
__global__ __launch_bounds__(256) void eproj_pack(
    const float* __restrict__ A,
    const float* __restrict__ Wgl, const float* __restrict__ bgl, float* __restrict__ Egl,
    const float* __restrict__ Wpt, const float* __restrict__ bpt, float* __restrict__ Ept,
    const float* __restrict__ WqGl, const float* __restrict__ WqPt,
    float* __restrict__ WqGlP, float* __restrict__ WqPtP)
{
    __shared__ __align__(16) float As[16][68];
    __shared__ __align__(16) float Bs[16][68];
    const int tid = threadIdx.x;

    if (blockIdx.x >= 6400) {
        const int p = blockIdx.x - 6400;       // [0,512)
        const int sel = p >> 8;
        const int k = p & 255;
        const float* src = sel ? WqPt : WqGl;
        float*       dst = sel ? WqPtP : WqGlP;
        dst[((size_t)(k >> 2) * 256 + tid) * 4 + (k & 3)] = src[(size_t)tid * 256 + k];
        return;
    }

    const int tx = tid & 15, ty = tid >> 4;
    const int ml = tid >> 2;
    const int kb = (tid & 3) << 2;

    const int x = blockIdx.x;
    const int xcd = x & 7;
    const int j = x >> 3;
    const int mt = xcd * 100 + (j >> 3);
    const int sel = (j >> 2) & 1;
    const int nt = j & 3;
    const float* W    = sel ? Wpt : Wgl;
    const float* bias = sel ? bpt : bgl;
    float*       Eo   = sel ? Ept : Egl;
    const int m0 = mt * 64, n0 = nt * 64;

    float4 a4 = *(const float4*)(A + (size_t)(m0 + ml) * 256 + kb);
    float4 b4 = *(const float4*)(W + (size_t)(n0 + ml) * 256 + kb);

    float acc[4][4] = {};
    for (int k0 = 0; k0 < 256; k0 += 16) {
        As[kb+0][ml] = a4.x; As[kb+1][ml] = a4.y; As[kb+2][ml] = a4.z; As[kb+3][ml] = a4.w;
        Bs[kb+0][ml] = b4.x; Bs[kb+1][ml] = b4.y; Bs[kb+2][ml] = b4.z; Bs[kb+3][ml] = b4.w;
        __syncthreads();
        int k1 = k0 + 16;
        if (k1 < 256) {
            a4 = *(const float4*)(A + (size_t)(m0 + ml) * 256 + k1 + kb);
            b4 = *(const float4*)(W + (size_t)(n0 + ml) * 256 + k1 + kb);
        }
#pragma unroll
        for (int kk = 0; kk < 16; kk++) {
            float4 av = *(const float4*)(&As[kk][ty << 2]);
            float4 bv = *(const float4*)(&Bs[kk][tx << 2]);
            float a_[4] = {av.x, av.y, av.z, av.w};
            float b_[4] = {bv.x, bv.y, bv.z, bv.w};
#pragma unroll
            for (int i = 0; i < 4; i++)
#pragma unroll
                for (int j2 = 0; j2 < 4; j2++) acc[i][j2] = fmaf(a_[i], b_[j2], acc[i][j2]);
        }
        __syncthreads();
    }
#pragma unroll
    for (int i = 0; i < 4; i++) {
        int m = m0 + (ty << 2) + i;
        int bb = m & (Bsz - 1);
        int ll = m >> 10;
#pragma unroll
        for (int j2 = 0; j2 < 4; j2++) {
            int n = n0 + (tx << 2) + j2;
            Eo[(size_t)bb * Lsz * Hsz + (size_t)ll * Hsz + n] = acc[i][j2] + bias[n];
        }
    }
}

// ============================================================
// K1: fused LSTM, 32 rows x 64 gate-cols per block -> 512 blocks.
// Same micro-kernel / staging order / epilogue as the verified
// round-0 kernel (bit-identical h/c), but BK=32 with DOUBLE-
// BUFFERED LDS: one barrier per K-tile -> 16 barriers (was 64).
// B is staged as two k-halves (kbB and kbB+16) so the LDS write
// bank pattern matches the old 4-way level.
// ============================================================
__global__ __launch_bounds__(256) void lstm_fused(
    const float* __restrict__ dec, const float* __restrict__ hprev,
    const float* __restrict__ cin,
    const float* __restrict__ Wih, const float* __restrict__ Whh,
    const float* __restrict__ bih, const float* __restrict__ bhh,
    float* __restrict__ hout, float* __restrict__ cout)
{
    __shared__ __align__(16) float As[2][32][36];
    __shared__ __align__(16) float Bs[2][32][68];
    const int tid = threadIdx.x;
    const int tx = tid & 15, ty = tid >> 4;
    const int mlA = tid >> 3;                 // [0,32)
    const int kbA = (tid & 7) << 2;           // {0,4,...,28}
    const int mlB = tid >> 2;                 // [0,64)
    const int kbB = (tid & 3) << 2;           // {0,4,8,12}, halves at +0/+16
    const int m0 = blockIdx.x * 32;
    const int hh0 = blockIdx.y * 16;
    const int wrow = ((mlB >> 4) << 8) + hh0 + (mlB & 15);
    const int pcol = ((mlB & 15) << 2) + (mlB >> 4);

    float4 a4  = *(const float4*)(dec + (size_t)(m0 + mlA) * 256 + kbA);
    float4 b4a = *(const float4*)(Wih + (size_t)wrow * 256 + kbB);
    float4 b4b = *(const float4*)(Wih + (size_t)wrow * 256 + 16 + kbB);

    // prologue: stage tile 0 into buffer 0
    As[0][kbA+0][mlA] = a4.x; As[0][kbA+1][mlA] = a4.y;
    As[0][kbA+2][mlA] = a4.z; As[0][kbA+3][mlA] = a4.w;
    Bs[0][kbB+0][pcol] = b4a.x; Bs[0][kbB+1][pcol] = b4a.y;
    Bs[0][kbB+2][pcol] = b4a.z; Bs[0][kbB+3][pcol] = b4a.w;
    Bs[0][16+kbB+0][pcol] = b4b.x; Bs[0][16+kbB+1][pcol] = b4b.y;
    Bs[0][16+kbB+2][pcol] = b4b.z; Bs[0][16+kbB+3][pcol] = b4b.w;
    __syncthreads();

    float acc[2][4] = {};
    for (int kt = 0; kt < 16; kt++) {
        const int cur = kt & 1;
        if (kt < 15) {
            const int k1 = (kt + 1) << 5;
            const float* Ap = (k1 < 256) ? dec : hprev;
            const float* Wp = (k1 < 256) ? Wih : Whh;
            const int kk0 = k1 & 255;
            a4  = *(const float4*)(Ap + (size_t)(m0 + mlA) * 256 + kk0 + kbA);
            b4a = *(const float4*)(Wp + (size_t)wrow * 256 + kk0 + kbB);
            b4b = *(const float4*)(Wp + (size_t)wrow * 256 + kk0 + 16 + kbB);
        }
#pragma unroll
        for (int kk = 0; kk < 32; kk++) {
            float2 av = *(const float2*)(&As[cur][kk][ty << 1]);
            float4 bv = *(const float4*)(&Bs[cur][kk][tx << 2]);
            acc[0][0] = fmaf(av.x, bv.x, acc[0][0]);
            acc[0][1] = fmaf(av.x, bv.y, acc[0][1]);
            acc[0][2] = fmaf(av.x, bv.z, acc[0][2]);
            acc[0][3] = fmaf(av.x, bv.w, acc[0][3]);
            acc[1][0] = fmaf(av.y, bv.x, acc[1][0]);
            acc[1][1] = fmaf(av.y, bv.y, acc[1][1]);
            acc[1][2] = fmaf(av.y, bv.z, acc[1][2]);
            acc[1][3] = fmaf(av.y, bv.w, acc[1][3]);
        }
        if (kt < 15) {
            const int nxt = cur ^ 1;
            As[nxt][kbA+0][mlA] = a4.x; As[nxt][kbA+1][mlA] = a4.y;
            As[nxt][kbA+2][mlA] = a4.z; As[nxt][kbA+3][mlA] = a4.w;
            Bs[nxt][kbB+0][pcol] = b4a.x; Bs[nxt][kbB+1][pcol] = b4a.y;
            Bs[nxt][kbB+2][pcol] = b4a.z; Bs[nxt][kbB+3][pcol] = b4a.w;
            Bs[nxt][16+kbB+0][pcol] = b4b.x; Bs[nxt][16+kbB+1][pcol] = b4b.y;
            Bs[nxt][16+kbB+2][pcol] = b4b.z; Bs[nxt][16+kbB+3][pcol] = b4b.w;
            __syncthreads();
        }
    }

    const int hh = hh0 + tx;
    const float bi0 = bih[hh]       + bhh[hh];
    const float bf  = bih[256 + hh] + bhh[256 + hh];
    const float bg  = bih[512 + hh] + bhh[512 + hh];
    const float bo  = bih[768 + hh] + bhh[768 + hh];
#pragma unroll
    for (int i = 0; i < 2; i++) {
        int m = m0 + (ty << 1) + i;
        float gi = acc[i][0] + bi0;
        float gf = acc[i][1] + bf;
        float gc = acc[i][2] + bg;
        float go = acc[i][3] + bo;
        float ii = 1.0f / (1.0f + expf(-gi));
        float ff = 1.0f / (1.0f + expf(-gf));
        float oo = 1.0f / (1.0f + expf(-go));
        float c2 = ff * cin[(size_t)m * 256 + hh] + ii * tanhf(gc);
        hout[(size_t)m * 256 + hh] = oo * tanhf(c2);
        cout[(size_t)m * 256 + hh] = c2;
    }
}

// ============================================================
// K2: fused glimpse + pointer attention, ONE row per block,
// 256 threads, 1024 blocks, 4 blocks/CU (R5 structure — best).
// Piggybacked DMA prefetch extended to ALL THREE e-phases:
//  * gl-matvec issues e_gl rows 0-31 into e_ls (1 DMA/iter, 8/wave)
//    -> glimpse-u AND mix read rows <32 from LDS.
//  * pt-matvec issues e_pt rows 0-31 into e_ls (after mix's barrier)
//    -> pointer-u reads rows <32 from LDS (as in round 5).
// Same bytes, same chain order -> bit-identical.  LDS 35.9KB.
// ============================================================
__global__ __launch_bounds__(256) void attn_row(
    const float* __restrict__ h,
    const float* __restrict__ WqGlP, const float* __restrict__ glbq,
    const float* __restrict__ e_gl, const float* __restrict__ glv,
    const float* __restrict__ WqPtP, const float* __restrict__ ptbq,
    const float* __restrict__ e_pt, const float* __restrict__ ptv,
    int* __restrict__ mask, float* __restrict__ out, int t,
    float* __restrict__ dec, const float* __restrict__ emb)
{
    __shared__ __align__(16) float e_ls[32][256];   // e prefetch (32KB)
    __shared__ __align__(16) float h_s[256];
    __shared__ __align__(16) float q_s[256];
    __shared__ __align__(16) float g_s[256];
    __shared__ float u_s[64];
    __shared__ float p_s[64];
    __shared__ int sel_s;

    const int tid = threadIdx.x;
    const int lane = tid & 63, wave = tid >> 6;
    const int b = blockIdx.x;

    const float* ebg = e_gl + (size_t)b * Lsz * 256;
    const float* ebp = e_pt + (size_t)b * Lsz * 256;

    h_s[tid] = h[(size_t)b * 256 + tid];
    __syncthreads();

    // ---- glimpse query matvec + e_gl rows 0-31 DMA piggyback ----
    {
        float q = glbq[tid];
        const float4* Wp = (const float4*)WqGlP;
#pragma unroll 8
        for (int k4 = 0; k4 < 64; k4++) {
            if (k4 < 32 && wave == (k4 & 3))
                gl_lds16(ebg + (size_t)k4 * 256 + (lane << 2), &e_ls[k4][0]);
            float4 w  = Wp[(size_t)k4 * 256 + tid];
            float4 hv = ((const float4*)h_s)[k4];
            q = fmaf(hv.x, w.x, q);
            q = fmaf(hv.y, w.y, q);
            q = fmaf(hv.z, w.z, q);
            q = fmaf(hv.w, w.w, q);
        }
        q_s[tid] = q;
    }
    __syncthreads();   // drains DMAs: e_ls[0..31] = e_gl rows 0..31

    // ---- glimpse u (rows <32 from LDS, rest global) ----
    {
        const float4 q4 = ((const float4*)q_s)[lane];
        const float4 v4 = ((const float4*)glv)[lane];
#pragma unroll
        for (int lp = 0; lp < 13; lp++) {
            const int l = lp * 4 + wave;
            float x = 0.0f;
            if (l < Lsz) {
                float4 e4;
                if (lp < 8) e4 = *(const float4*)(&e_ls[l][lane << 2]);
                else        e4 = *(const float4*)(ebg + (size_t)l * 256 + (lane << 2));
                x  = v4.x * tanhf(q4.x + e4.x);
                x += v4.y * tanhf(q4.y + e4.y);
                x += v4.z * tanhf(q4.z + e4.z);
                x += v4.w * tanhf(q4.w + e4.w);
            }
#pragma unroll
            for (int o = 32; o > 0; o >>= 1) x += __shfl_xor(x, o, 64);
            if (lane == 0 && l < Lsz) u_s[l] = x;
        }
    }
    __syncthreads();

    // ---- glimpse softmax (wave 0, lane-parallel) ----
    if (wave == 0) {
        const int l = lane;
        const int ml = (l < Lsz && t > 0) ? mask[b * Lsz + l] : 0;
        float logit = (l < Lsz) ? (ml ? NEGV : u_s[l]) : -1e30f;
        float m = logit;
#pragma unroll
        for (int o = 32; o > 0; o >>= 1) m = fmaxf(m, __shfl_xor(m, o, 64));
        float ex = (l < Lsz) ? expf(logit - m) : 0.0f;
        float den = ex;
#pragma unroll
        for (int o = 32; o > 0; o >>= 1) den += __shfl_xor(den, o, 64);
        if (l < Lsz) p_s[l] = ex / den;
    }
    __syncthreads();

    // ---- glimpse mix (rows <32 from LDS, rest L2-hot; exact l order) ----
    {
        float acc = 0.0f;
        const float* ebh = ebg + tid;
#pragma unroll
        for (int l = 0; l < Lsz; l++) {
            float ev = (l < 32) ? e_ls[l][tid] : ebh[(size_t)l * 256];
            acc = fmaf(p_s[l], ev, acc);
        }
        g_s[tid] = acc;
    }
    __syncthreads();

    // ---- pointer query matvec + e_pt rows 0-31 DMA piggyback ----
    {
        float p = ptbq[tid];
        const float4* Wp = (const float4*)WqPtP;
#pragma unroll 8
        for (int k4 = 0; k4 < 64; k4++) {
            if (k4 < 32 && wave == (k4 & 3))
                gl_lds16(ebp + (size_t)k4 * 256 + (lane << 2), &e_ls[k4][0]);
            float4 w  = Wp[(size_t)k4 * 256 + tid];
            float4 gv = ((const float4*)g_s)[k4];
            p = fmaf(gv.x, w.x, p);
            p = fmaf(gv.y, w.y, p);
            p = fmaf(gv.z, w.z, p);
            p = fmaf(gv.w, w.w, p);
        }
        q_s[tid] = p;
    }
    __syncthreads();   // drains DMAs: e_ls[0..31] = e_pt rows 0..31

    // ---- pointer u (rows <32 from LDS, rest global) ----
    {
        const float4 q4 = ((const float4*)q_s)[lane];
        const float4 v4 = ((const float4*)ptv)[lane];
#pragma unroll
        for (int lp = 0; lp < 13; lp++) {
            const int l = lp * 4 + wave;
            float x = 0.0f;
            if (l < Lsz) {
                float4 e4;
                if (lp < 8) e4 = *(const float4*)(&e_ls[l][lane << 2]);
                else        e4 = *(const float4*)(ebp + (size_t)l * 256 + (lane << 2));
                x  = v4.x * tanhf(q4.x + e4.x);
                x += v4.y * tanhf(q4.y + e4.y);
                x += v4.z * tanhf(q4.z + e4.z);
                x += v4.w * tanhf(q4.w + e4.w);
            }
#pragma unroll
            for (int o = 32; o > 0; o >>= 1) x += __shfl_xor(x, o, 64);
            if (lane == 0 && l < Lsz) u_s[l] = x;
        }
    }
    __syncthreads();

    // ---- pointer softmax + argmax + log_p + mask update (wave 0) ----
    if (wave == 0) {
        const int l = lane;
        const int ml = (l < Lsz && t > 0) ? mask[b * Lsz + l] : 0;
        float logit;
        if (l < Lsz) {
            float u = u_s[l];
            logit = 10.0f * tanhf(u);
            if (ml) logit = NEGV;
        } else logit = -1e30f;

        float m = logit;
#pragma unroll
        for (int o = 32; o > 0; o >>= 1) m = fmaxf(m, __shfl_xor(m, o, 64));
        float ex = (l < Lsz) ? expf(logit - m) : 0.0f;
        float den = ex;
#pragma unroll
        for (int o = 32; o > 0; o >>= 1) den += __shfl_xor(den, o, 64);

        // argmax with first-index tie-break
        float av = logit; int ai = (l < Lsz) ? l : 63;
#pragma unroll
        for (int o = 32; o > 0; o >>= 1) {
            float ov = __shfl_xor(av, o, 64);
            int   oi = __shfl_xor(ai, o, 64);
            if (ov > av || (ov == av && oi < ai)) { av = ov; ai = oi; }
        }
        const float lse = m + logf(den);
        if (l < Lsz)
            out[(size_t)b * Lsz * Lsz + (size_t)t * Lsz + l] = logit - lse;
        if (l == 0) {
            out[(size_t)Bsz * Lsz * Lsz + (size_t)b * Lsz + t] = (float)ai;
            sel_s = ai;
        }
        int newm = ml | (l == ai);
        unsigned long long bal = __ballot(l >= Lsz ? 1 : newm);
        int all = (bal == 0xFFFFFFFFFFFFFFFFull);
        if (l < Lsz) mask[b * Lsz + l] = (all && l == Lsz - 1) ? 0 : newm;
    }
    __syncthreads();

    // ---- gather next decoder input ----
    {
        const int s = sel_s;
        dec[(size_t)b * 256 + tid] = emb[(size_t)s * Bsz * 256 + (size_t)b * 256 + tid];
    }
}

// ============================================================
extern "C" void kernel_launch(void* const* d_in, const int* in_sizes, int n_in,
                              void* d_out, int out_size, void* d_ws, size_t ws_size,
                              hipStream_t stream) {
    const float* decoder_input = (const float*)d_in[0];
    const float* emb           = (const float*)d_in[1];   // [L,B,E]
    const float* h0            = (const float*)d_in[2];
    const float* c0            = (const float*)d_in[3];
    const float* context       = (const float*)d_in[4];   // [L,B,H]
    const float* Wih    = (const float*)d_in[6];
    const float* Whh    = (const float*)d_in[7];
    const float* bih    = (const float*)d_in[8];
    const float* bhh    = (const float*)d_in[9];
    const float* glWq   = (const float*)d_in[10];
    const float* glbq   = (const float*)d_in[11];
    const float* glWref = (const float*)d_in[12];
    const float* glbref = (const float*)d_in[13];
    const float* glv    = (const float*)d_in[14];
    const float* ptWq   = (const float*)d_in[15];
    const float* ptbq   = (const float*)d_in[16];
    const float* ptWref = (const float*)d_in[17];
    const float* ptbref = (const float*)d_in[18];
    const float* ptv    = (const float*)d_in[19];

    float* out = (float*)d_out;

    // workspace layout (floats)
    float* ws    = (float*)d_ws;
    float* e_gl  = ws;                                    // [B,L,H]
    float* e_pt  = e_gl + (size_t)Bsz * Lsz * Hsz;        // [B,L,H]
    float* WqGlP = e_pt + (size_t)Bsz * Lsz * Hsz;        // [H,H] packed
    float* WqPtP = WqGlP + (size_t)Hsz * Hsz;
    float* hb0   = WqPtP + (size_t)Hsz * Hsz;
    float* hb1   = hb0 + (size_t)Bsz * Hsz;
    float* cb0   = hb1 + (size_t)Bsz * Hsz;
    float* cb1   = cb0 + (size_t)Bsz * Hsz;
    float* dec   = cb1 + (size_t)Bsz * Hsz;
    int*   mask  = (int*)(dec + (size_t)Bsz * Esz);       // [B,L]

    float* hbuf[2] = {hb0, hb1};
    float* cbuf[2] = {cb0, cb1};

    // one-time: e-projection GEMMs + Wq pack, single dispatch
    eproj_pack<<<dim3(6912), dim3(256), 0, stream>>>(
        context, glWref, glbref, e_gl, ptWref, ptbref, e_pt,
        glWq, ptWq, WqGlP, WqPtP);

    for (int t = 0; t < Lsz; t++) {
        const float* Ain = (t == 0) ? decoder_input : dec;
        const float* hin = (t == 0) ? h0 : hbuf[(t + 1) & 1];
        const float* cin = (t == 0) ? c0 : cbuf[(t + 1) & 1];
        float* hout = hbuf[t & 1];
        float* cout = cbuf[t & 1];

        lstm_fused<<<dim3(32, 16), dim3(256), 0, stream>>>(
            Ain, hin, cin, Wih, Whh, bih, bhh, hout, cout);

        attn_row<<<dim3(1024), dim3(256), 0, stream>>>(
            hout, WqGlP, glbq, e_gl, glv, WqPtP, ptbq, e_pt, ptv,
            mask, out, t, dec, emb);
    }
}

// Round 9
// 4039.756 us; speedup vs baseline: 1.1441x; 1.0114x over previous
//
#include <hip/hip_runtime.h>
#include <math.h>

#define Bsz 1024
#define Lsz 50
#define Esz 256
#define Hsz 256
#define NEGV (-1e9f)

// async global->LDS 16B copy: per-lane global addr, wave-uniform LDS base
// (HW writes base + lane*16).  Falls back to reg staging if unavailable.
__device__ __forceinline__ void gl_lds16(const float* g, float* l) {
#if __has_builtin(__builtin_amdgcn_global_load_lds)
    __builtin_amdgcn_global_load_lds(
        (const __attribute__((address_space(1))) unsigned int*)g,
        (__attribute__((address_space(3))) unsigned int*)l, 16, 0, 0);
#else
    *(float4*)l = *(const float4*)g;
#endif
}

// ============================================================
// e-projection GEMM (one-time) + Wq k-major pack fused into one
// dispatch.  Blocks [0,6400): eproj exactly as the verified kernel.
// Blocks [6400,6912): pack_wq (runs in eproj's shadow).
// ============================================================
__global__ __launch_bounds__(256) void eproj_pack(
    const float* __restrict__ A,
    const float* __restrict__ Wgl, const float* __restrict__ bgl, float* __restrict__ Egl,
    const float* __restrict__ Wpt, const float* __restrict__ bpt, float* __restrict__ Ept,
    const float* __restrict__ WqGl, const float* __restrict__ WqPt,
    float* __restrict__ WqGlP, float* __restrict__ WqPtP)
{
    __shared__ __align__(16) float As[16][68];
    __shared__ __align__(16) float Bs[16][68];
    const int tid = threadIdx.x;

    if (blockIdx.x >= 6400) {
        const int p = blockIdx.x - 6400;       // [0,512)
        const int sel = p >> 8;
        const int k = p & 255;
        const float* src = sel ? WqPt : WqGl;
        float*       dst = sel ? WqPtP : WqGlP;
        dst[((size_t)(k >> 2) * 256 + tid) * 4 + (k & 3)] = src[(size_t)tid * 256 + k];
        return;
    }

    const int tx = tid & 15, ty = tid >> 4;
    const int ml = tid >> 2;
    const int kb = (tid & 3) << 2;

    const int x = blockIdx.x;
    const int xcd = x & 7;
    const int j = x >> 3;
    const int mt = xcd * 100 + (j >> 3);
    const int sel = (j >> 2) & 1;
    const int nt = j & 3;
    const float* W    = sel ? Wpt : Wgl;
    const float* bias = sel ? bpt : bgl;
    float*       Eo   = sel ? Ept : Egl;
    const int m0 = mt * 64, n0 = nt * 64;

    float4 a4 = *(const float4*)(A + (size_t)(m0 + ml) * 256 + kb);
    float4 b4 = *(const float4*)(W + (size_t)(n0 + ml) * 256 + kb);

    float acc[4][4] = {};
    for (int k0 = 0; k0 < 256; k0 += 16) {
        As[kb+0][ml] = a4.x; As[kb+1][ml] = a4.y; As[kb+2][ml] = a4.z; As[kb+3][ml] = a4.w;
        Bs[kb+0][ml] = b4.x; Bs[kb+1][ml] = b4.y; Bs[kb+2][ml] = b4.z; Bs[kb+3][ml] = b4.w;
        __syncthreads();
        int k1 = k0 + 16;
        if (k1 < 256) {
            a4 = *(const float4*)(A + (size_t)(m0 + ml) * 256 + k1 + kb);
            b4 = *(const float4*)(W + (size_t)(n0 + ml) * 256 + k1 + kb);
        }
#pragma unroll
        for (int kk = 0; kk < 16; kk++) {
            float4 av = *(const float4*)(&As[kk][ty << 2]);
            float4 bv = *(const float4*)(&Bs[kk][tx << 2]);
            float a_[4] = {av.x, av.y, av.z, av.w};
            float b_[4] = {bv.x, bv.y, bv.z, bv.w};
#pragma unroll
            for (int i = 0; i < 4; i++)
#pragma unroll
                for (int j2 = 0; j2 < 4; j2++) acc[i][j2] = fmaf(a_[i], b_[j2], acc[i][j2]);
        }
        __syncthreads();
    }
#pragma unroll
    for (int i = 0; i < 4; i++) {
        int m = m0 + (ty << 2) + i;
        int bb = m & (Bsz - 1);
        int ll = m >> 10;
#pragma unroll
        for (int j2 = 0; j2 < 4; j2++) {
            int n = n0 + (tx << 2) + j2;
            Eo[(size_t)bb * Lsz * Hsz + (size_t)ll * Hsz + n] = acc[i][j2] + bias[n];
        }
    }
}

// ============================================================
// K1: fused LSTM, 64 rows x 64 gate-cols per block -> grid (16,16)
// = 256 blocks, 4x4 register tile (eproj structure: 2 ds_read_b128
// per 16 FMAs, halving DS-instruction pressure vs the 2x4 tile).
// Per-output chain unchanged: single accumulator, k ascending
// 0..511, dec tiles then h tiles, same 16-wide tile order
// -> bit-identical h/c.  Gate permutation wrow/pcol as before.
// ============================================================
__global__ __launch_bounds__(256) void lstm_fused(
    const float* __restrict__ dec, const float* __restrict__ hprev,
    const float* __restrict__ cin,
    const float* __restrict__ Wih, const float* __restrict__ Whh,
    const float* __restrict__ bih, const float* __restrict__ bhh,
    float* __restrict__ hout, float* __restrict__ cout)
{
    __shared__ __align__(16) float As[16][68];
    __shared__ __align__(16) float Bs[16][68];
    const int tid = threadIdx.x;
    const int tx = tid & 15, ty = tid >> 4;
    const int ml = tid >> 2;                  // [0,64)
    const int kb = (tid & 3) << 2;            // {0,4,8,12}
    const int m0  = blockIdx.x * 64;
    const int hh0 = blockIdx.y * 16;
    const int wrow = ((ml >> 4) << 8) + hh0 + (ml & 15);   // gate*256 + hh
    const int pcol = ((ml & 15) << 2) + (ml >> 4);         // hcol*4 + gate

    float4 a4 = *(const float4*)(dec + (size_t)(m0 + ml) * 256 + kb);
    float4 b4 = *(const float4*)(Wih + (size_t)wrow * 256 + kb);

    float acc[4][4] = {};
    for (int k0 = 0; k0 < 512; k0 += 16) {
        As[kb+0][ml] = a4.x; As[kb+1][ml] = a4.y; As[kb+2][ml] = a4.z; As[kb+3][ml] = a4.w;
        Bs[kb+0][pcol] = b4.x; Bs[kb+1][pcol] = b4.y;
        Bs[kb+2][pcol] = b4.z; Bs[kb+3][pcol] = b4.w;
        __syncthreads();
        int k1 = k0 + 16;
        if (k1 < 512) {
            const float* Ap = (k1 < 256) ? dec : hprev;
            const float* Wp = (k1 < 256) ? Wih : Whh;
            int kk0 = k1 & 255;
            a4 = *(const float4*)(Ap + (size_t)(m0 + ml) * 256 + kk0 + kb);
            b4 = *(const float4*)(Wp + (size_t)wrow * 256 + kk0 + kb);
        }
#pragma unroll
        for (int kk = 0; kk < 16; kk++) {
            float4 av = *(const float4*)(&As[kk][ty << 2]);
            float4 bv = *(const float4*)(&Bs[kk][tx << 2]);
            float a_[4] = {av.x, av.y, av.z, av.w};
            float b_[4] = {bv.x, bv.y, bv.z, bv.w};
#pragma unroll
            for (int i = 0; i < 4; i++)
#pragma unroll
                for (int j2 = 0; j2 < 4; j2++)
                    acc[i][j2] = fmaf(a_[i], b_[j2], acc[i][j2]);
        }
        __syncthreads();
    }

    const int hh = hh0 + tx;
    const float bi0 = bih[hh]       + bhh[hh];
    const float bf  = bih[256 + hh] + bhh[256 + hh];
    const float bg  = bih[512 + hh] + bhh[512 + hh];
    const float bo  = bih[768 + hh] + bhh[768 + hh];
#pragma unroll
    for (int i = 0; i < 4; i++) {
        int m = m0 + (ty << 2) + i;
        float gi = acc[i][0] + bi0;
        float gf = acc[i][1] + bf;
        float gc = acc[i][2] + bg;
        float go = acc[i][3] + bo;
        float ii = 1.0f / (1.0f + expf(-gi));
        float ff = 1.0f / (1.0f + expf(-gf));
        float oo = 1.0f / (1.0f + expf(-go));
        float c2 = ff * cin[(size_t)m * 256 + hh] + ii * tanhf(gc);
        hout[(size_t)m * 256 + hh] = oo * tanhf(c2);
        cout[(size_t)m * 256 + hh] = c2;
    }
}

// ============================================================
// K2: fused glimpse + pointer attention, ONE row per block
// (1024 blocks, 4 blocks/CU) — the round-5 kernel VERBATIM
// (best measured: 4075us total).  Glimpse-u piggybacks e_pt
// rows <32 into LDS; pointer-u reads them from LDS.
// ============================================================
__global__ __launch_bounds__(256) void attn_row(
    const float* __restrict__ h,
    const float* __restrict__ WqGlP, const float* __restrict__ glbq,
    const float* __restrict__ e_gl, const float* __restrict__ glv,
    const float* __restrict__ WqPtP, const float* __restrict__ ptbq,
    const float* __restrict__ e_pt, const float* __restrict__ ptv,
    int* __restrict__ mask, float* __restrict__ out, int t,
    float* __restrict__ dec, const float* __restrict__ emb)
{
    __shared__ __align__(16) float e_ls[32][256];   // e_pt prefetch (32KB)
    __shared__ __align__(16) float h_s[256];
    __shared__ __align__(16) float q_s[256];
    __shared__ __align__(16) float g_s[256];
    __shared__ float u_s[64];
    __shared__ float p_s[64];
    __shared__ int sel_s;

    const int tid = threadIdx.x;
    const int lane = tid & 63, wave = tid >> 6;
    const int b = blockIdx.x;

    h_s[tid] = h[(size_t)b * 256 + tid];
    __syncthreads();

    // ---- glimpse query matvec (packed weights) ----
    {
        float q = glbq[tid];
        const float4* Wp = (const float4*)WqGlP;
#pragma unroll 8
        for (int k4 = 0; k4 < 64; k4++) {
            float4 w  = Wp[(size_t)k4 * 256 + tid];
            float4 hv = ((const float4*)h_s)[k4];
            q = fmaf(hv.x, w.x, q);
            q = fmaf(hv.y, w.y, q);
            q = fmaf(hv.z, w.z, q);
            q = fmaf(hv.w, w.w, q);
        }
        q_s[tid] = q;
    }
    __syncthreads();

    const float* ebg = e_gl + (size_t)b * Lsz * 256;
    const float* ebp = e_pt + (size_t)b * Lsz * 256;
    {
        const float4 q4 = ((const float4*)q_s)[lane];
        const float4 v4 = ((const float4*)glv)[lane];
#pragma unroll
        for (int lp = 0; lp < 13; lp++) {
            const int l = lp * 4 + wave;
            // piggyback: async-prefetch e_pt row l (<32) into LDS.
            if (lp < 8)
                gl_lds16(ebp + (size_t)l * 256 + (lane << 2), &e_ls[l][0]);
            float x = 0.0f;
            if (l < Lsz) {
                float4 e4 = *(const float4*)(ebg + (size_t)l * 256 + (lane << 2));
                x  = v4.x * tanhf(q4.x + e4.x);
                x += v4.y * tanhf(q4.y + e4.y);
                x += v4.z * tanhf(q4.z + e4.z);
                x += v4.w * tanhf(q4.w + e4.w);
            }
#pragma unroll
            for (int o = 32; o > 0; o >>= 1) x += __shfl_xor(x, o, 64);
            if (lane == 0 && l < Lsz) u_s[l] = x;
        }
    }
    __syncthreads();

    // ---- glimpse softmax (wave 0, lane-parallel) ----
    if (wave == 0) {
        const int l = lane;
        const int ml = (l < Lsz && t > 0) ? mask[b * Lsz + l] : 0;
        float logit = (l < Lsz) ? (ml ? NEGV : u_s[l]) : -1e30f;
        float m = logit;
#pragma unroll
        for (int o = 32; o > 0; o >>= 1) m = fmaxf(m, __shfl_xor(m, o, 64));
        float ex = (l < Lsz) ? expf(logit - m) : 0.0f;
        float den = ex;
#pragma unroll
        for (int o = 32; o > 0; o >>= 1) den += __shfl_xor(den, o, 64);
        if (l < Lsz) p_s[l] = ex / den;
    }
    __syncthreads();

    // ---- glimpse mix (L2-hot re-read, exact l order) ----
    {
        float acc = 0.0f;
        const float* ebh = ebg + tid;
#pragma unroll
        for (int l = 0; l < Lsz; l++)
            acc = fmaf(p_s[l], ebh[(size_t)l * 256], acc);
        g_s[tid] = acc;
    }
    __syncthreads();

    // ---- pointer query matvec (packed weights) ----
    {
        float p = ptbq[tid];
        const float4* Wp = (const float4*)WqPtP;
#pragma unroll 8
        for (int k4 = 0; k4 < 64; k4++) {
            float4 w  = Wp[(size_t)k4 * 256 + tid];
            float4 gv = ((const float4*)g_s)[k4];
            p = fmaf(gv.x, w.x, p);
            p = fmaf(gv.y, w.y, p);
            p = fmaf(gv.z, w.z, p);
            p = fmaf(gv.w, w.w, p);
        }
        q_s[tid] = p;
    }
    __syncthreads();

    {
        const float4 q4 = ((const float4*)q_s)[lane];
        const float4 v4 = ((const float4*)ptv)[lane];
#pragma unroll
        for (int lp = 0; lp < 13; lp++) {
            const int l = lp * 4 + wave;
            float x = 0.0f;
            if (l < Lsz) {
                // rows l<32 (lp<8) were prefetched to LDS: same bytes,
                // same consumption order -> bit-identical.
                float4 e4;
                if (lp < 8) e4 = *(const float4*)(&e_ls[l][lane << 2]);
                else        e4 = *(const float4*)(ebp + (size_t)l * 256 + (lane << 2));
                x  = v4.x * tanhf(q4.x + e4.x);
                x += v4.y * tanhf(q4.y + e4.y);
                x += v4.z * tanhf(q4.z + e4.z);
                x += v4.w * tanhf(q4.w + e4.w);
            }
#pragma unroll
            for (int o = 32; o > 0; o >>= 1) x += __shfl_xor(x, o, 64);
            if (lane == 0 && l < Lsz) u_s[l] = x;
        }
    }
    __syncthreads();

    // ---- pointer softmax + argmax + log_p + mask update (wave 0) ----
    if (wave == 0) {
        const int l = lane;
        const int ml = (l < Lsz && t > 0) ? mask[b * Lsz + l] : 0;
        float logit;
        if (l < Lsz) {
            float u = u_s[l];
            logit = 10.0f * tanhf(u);
            if (ml) logit = NEGV;
        } else logit = -1e30f;

        float m = logit;
#pragma unroll
        for (int o = 32; o > 0; o >>= 1) m = fmaxf(m, __shfl_xor(m, o, 64));
        float ex = (l < Lsz) ? expf(logit - m) : 0.0f;
        float den = ex;
#pragma unroll
        for (int o = 32; o > 0; o >>= 1) den += __shfl_xor(den, o, 64);

        // argmax with first-index tie-break
        float av = logit; int ai = (l < Lsz) ? l : 63;
#pragma unroll
        for (int o = 32; o > 0; o >>= 1) {
            float ov = __shfl_xor(av, o, 64);
            int   oi = __shfl_xor(ai, o, 64);
            if (ov > av || (ov == av && oi < ai)) { av = ov; ai = oi; }
        }
        const float lse = m + logf(den);
        if (l < Lsz)
            out[(size_t)b * Lsz * Lsz + (size_t)t * Lsz + l] = logit - lse;
        if (l == 0) {
            out[(size_t)Bsz * Lsz * Lsz + (size_t)b * Lsz + t] = (float)ai;
            sel_s = ai;
        }
        int newm = ml | (l == ai);
        unsigned long long bal = __ballot(l >= Lsz ? 1 : newm);
        int all = (bal == 0xFFFFFFFFFFFFFFFFull);
        if (l < Lsz) mask[b * Lsz + l] = (all && l == Lsz - 1) ? 0 : newm;
    }
    __syncthreads();

    // ---- gather next decoder input ----
    {
        const int s = sel_s;
        dec[(size_t)b * 256 + tid] = emb[(size_t)s * Bsz * 256 + (size_t)b * 256 + tid];
    }
}

// ============================================================
extern "C" void kernel_launch(void* const* d_in, const int* in_sizes, int n_in,
                              void* d_out, int out_size, void* d_ws, size_t ws_size,
                              hipStream_t stream) {
    const float* decoder_input = (const float*)d_in[0];
    const float* emb           = (const float*)d_in[1];   // [L,B,E]
    const float* h0            = (const float*)d_in[2];
    const float* c0            = (const float*)d_in[3];
    const float* context       = (const float*)d_in[4];   // [L,B,H]
    const float* Wih    = (const float*)d_in[6];
    const float* Whh    = (const float*)d_in[7];
    const float* bih    = (const float*)d_in[8];
    const float* bhh    = (const float*)d_in[9];
    const float* glWq   = (const float*)d_in[10];
    const float* glbq   = (const float*)d_in[11];
    const float* glWref = (const float*)d_in[12];
    const float* glbref = (const float*)d_in[13];
    const float* glv    = (const float*)d_in[14];
    const float* ptWq   = (const float*)d_in[15];
    const float* ptbq   = (const float*)d_in[16];
    const float* ptWref = (const float*)d_in[17];
    const float* ptbref = (const float*)d_in[18];
    const float* ptv    = (const float*)d_in[19];

    float* out = (float*)d_out;

    // workspace layout (floats)
    float* ws    = (float*)d_ws;
    float* e_gl  = ws;                                    // [B,L,H]
    float* e_pt  = e_gl + (size_t)Bsz * Lsz * Hsz;        // [B,L,H]
    float* WqGlP = e_pt + (size_t)Bsz * Lsz * Hsz;        // [H,H] packed
    float* WqPtP = WqGlP + (size_t)Hsz * Hsz;
    float* hb0   = WqPtP + (size_t)Hsz * Hsz;
    float* hb1   = hb0 + (size_t)Bsz * Hsz;
    float* cb0   = hb1 + (size_t)Bsz * Hsz;
    float* cb1   = cb0 + (size_t)Bsz * Hsz;
    float* dec   = cb1 + (size_t)Bsz * Hsz;
    int*   mask  = (int*)(dec + (size_t)Bsz * Esz);       // [B,L]

    float* hbuf[2] = {hb0, hb1};
    float* cbuf[2] = {cb0, cb1};

    // one-time: e-projection GEMMs + Wq pack, single dispatch
    eproj_pack<<<dim3(6912), dim3(256), 0, stream>>>(
        context, glWref, glbref, e_gl, ptWref, ptbref, e_pt,
        glWq, ptWq, WqGlP, WqPtP);

    for (int t = 0; t < Lsz; t++) {
        const float* Ain = (t == 0) ? decoder_input : dec;
        const float* hin = (t == 0) ? h0 : hbuf[(t + 1) & 1];
        const float* cin = (t == 0) ? c0 : cbuf[(t + 1) & 1];
        float* hout = hbuf[t & 1];
        float* cout = cbuf[t & 1];

        lstm_fused<<<dim3(16, 16), dim3(256), 0, stream>>>(
            Ain, hin, cin, Wih, Whh, bih, bhh, hout, cout);

        attn_row<<<dim3(1024), dim3(256), 0, stream>>>(
            hout, WqGlP, glbq, e_gl, glv, WqPtP, ptbq, e_pt, ptv,
            mask, out, t, dec, emb);
    }
}